// Round 1
// baseline (286.613 us; speedup 1.0000x reference)
//
#include <hip/hip_runtime.h>

#define N_ 64
#define C_ 4
#define D_ 2048
#define K_ 64
#define O_ 256
#define L_ 1985
#define CHUNK 512
#define NCH 4

typedef __attribute__((ext_vector_type(8))) short s16x8;
typedef __attribute__((ext_vector_type(4))) float f32x4;

__device__ __forceinline__ unsigned short f2bf(float f) {
    union { float f; unsigned u; } v; v.f = f;
    unsigned u = v.u;
    u += 0x7fffu + ((u >> 16) & 1u);   // round-to-nearest-even
    return (unsigned short)(u >> 16);
}

// Convert weight (O,C,K) fp32 -> bf16 in ws, and compute y_norm[o*C+c] in fp32.
__global__ __launch_bounds__(256) void prep_w(const float* __restrict__ w,
                                              unsigned short* __restrict__ wb,
                                              float* __restrict__ yn) {
    int o = blockIdx.x;
    int tid = threadIdx.x;
    int c = tid >> 6, k = tid & 63;           // wave w == channel c
    size_t idx = (size_t)(o * C_ + c) * K_ + k;
    float v = w[idx];
    wb[idx] = f2bf(v);
    float s = v * v;
    for (int off = 32; off > 0; off >>= 1) s += __shfl_down(s, off, 64);
    if (k == 0) yn[o * C_ + c] = s;
}

// One block = one (n,c) row x one 512-wide l-chunk. 4 waves, wave owns 64 o's.
__global__ __launch_bounds__(256, 2) void shapelet_main(const float* __restrict__ x,
                                                        const unsigned short* __restrict__ wb,
                                                        const float* __restrict__ yn,
                                                        float* __restrict__ out) {
    __shared__ float xf[CHUNK + 64];          // fp32 copy for exact x_norm
    __shared__ unsigned short xs0[CHUNK + 64];// bf16 copy
    __shared__ unsigned short xs1[CHUNK + 64];// bf16 copy shifted by 1 elem (alignment)
    __shared__ float xn[CHUNK];               // fp32 window sumsq

    int bid = blockIdx.x;
    int ch = bid & (NCH - 1);
    int nc = bid >> 2;                        // n*C + c
    int c  = nc & (C_ - 1);
    int l0c = ch * CHUNK;
    const float* xrow = x + (size_t)nc * D_;
    int tid = threadIdx.x;

    // Stage x slice [l0c, l0c+CHUNK+64) with zero-pad past D
    for (int i = tid; i < CHUNK + 64; i += 256) {
        int g = l0c + i;
        float v = (g < D_) ? xrow[g] : 0.f;
        xf[i] = v;
        unsigned short b = f2bf(v);
        xs0[i] = b;
        if (i > 0) xs1[i - 1] = b;
    }
    __syncthreads();
    // Exact fp32 x_norm per l in chunk
    for (int l = tid; l < CHUNK; l += 256) {
        float s = 0.f;
        #pragma unroll 16
        for (int k = 0; k < K_; ++k) { float v = xf[l + k]; s = fmaf(v, v, s); }
        xn[l] = s;
    }
    __syncthreads();

    int wave = tid >> 6, lane = tid & 63;
    int o0 = wave * 64;
    int lr = lane & 15, hi = lane >> 4;

    // A fragments: weights, 4 o-tiles x 2 k-steps, each lane 8 contiguous bf16 (16B aligned)
    s16x8 afr[4][2];
    #pragma unroll
    for (int ot = 0; ot < 4; ++ot)
        #pragma unroll
        for (int kk = 0; kk < 2; ++kk) {
            const unsigned short* p =
                wb + (size_t)((o0 + ot * 16 + lr) * C_ + c) * K_ + kk * 32 + hi * 8;
            afr[ot][kk] = *reinterpret_cast<const s16x8*>(p);
        }
    // y_norm values this lane will need (row = 4*hi + r within each o-tile)
    float ynv[16];
    #pragma unroll
    for (int ot = 0; ot < 4; ++ot)
        #pragma unroll
        for (int r = 0; r < 4; ++r)
            ynv[ot * 4 + r] = yn[(o0 + ot * 16 + hi * 4 + r) * C_ + c];

    int Lrem = L_ - l0c;
    int nv = Lrem < CHUNK ? Lrem : CHUNK;
    int nLT = (nv + 15) >> 4;

    const unsigned* xs0u = (const unsigned*)xs0;
    const unsigned* xs1u = (const unsigned*)xs1;
    float* orow = out + (size_t)nc * O_ * L_;

    for (int lt = 0; lt < nLT; ++lt) {
        f32x4 z = {0.f, 0.f, 0.f, 0.f};
        f32x4 acc[4] = {z, z, z, z};
        int e0 = lt * 16 + lr + hi * 8;
        #pragma unroll
        for (int kk = 0; kk < 2; ++kk) {
            int e = e0 + kk * 32;
            // B fragment: 8 consecutive bf16 of the x row starting at elem e.
            // Use the 1-shifted copy when e is odd so every ds_read_b32 is aligned.
            const unsigned* p = (e & 1) ? (xs1u + ((e - 1) >> 1)) : (xs0u + (e >> 1));
            union { unsigned u[4]; s16x8 v; } bb;
            bb.u[0] = p[0]; bb.u[1] = p[1]; bb.u[2] = p[2]; bb.u[3] = p[3];
            #pragma unroll
            for (int ot = 0; ot < 4; ++ot)
                acc[ot] = __builtin_amdgcn_mfma_f32_16x16x32_bf16(afr[ot][kk], bb.v,
                                                                  acc[ot], 0, 0, 0);
        }
        int ll = lt * 16 + lr;
        float xnv = xn[ll];
        int lg = l0c + ll;
        if (lg < L_) {
            #pragma unroll
            for (int ot = 0; ot < 4; ++ot) {
                int o = o0 + ot * 16 + hi * 4;
                float* po = orow + (size_t)o * L_ + lg;
                #pragma unroll
                for (int r = 0; r < 4; ++r) {
                    float vv = fmaxf(xnv + ynv[ot * 4 + r] - 2.f * acc[ot][r], 0.f)
                               * (1.f / (float)K_);
                    po[(size_t)r * L_] = vv;
                }
            }
        }
    }
}

extern "C" void kernel_launch(void* const* d_in, const int* in_sizes, int n_in,
                              void* d_out, int out_size, void* d_ws, size_t ws_size,
                              hipStream_t stream) {
    const float* x = (const float*)d_in[0];
    const float* w = (const float*)d_in[1];
    float* out = (float*)d_out;

    unsigned short* wb = (unsigned short*)d_ws;                       // 128 KiB
    float* yn = (float*)((char*)d_ws + (size_t)O_ * C_ * K_ * 2);     // 4 KiB

    prep_w<<<O_, 256, 0, stream>>>(w, wb, yn);
    shapelet_main<<<(size_t)N_ * C_ * NCH, 256, 0, stream>>>(x, wb, yn, out);
}

// Round 2
// 149.177 us; speedup vs baseline: 1.9213x; 1.9213x over previous
//
#include <hip/hip_runtime.h>

#define N_ 64
#define C_ 4
#define D_ 2048
#define K_ 64
#define O_ 256
#define L_ 1985
#define XS (D_ + 64)   // staged x row + zero pad

typedef __attribute__((ext_vector_type(8))) short s16x8;
typedef __attribute__((ext_vector_type(4))) float f32x4;

__device__ __forceinline__ unsigned short f2bf(float f) {
    union { float f; unsigned u; } v; v.f = f;
    unsigned u = v.u;
    u += 0x7fffu + ((u >> 16) & 1u);   // round-to-nearest-even
    return (unsigned short)(u >> 16);
}

// weight (O,C,K) fp32 -> bf16, plus y_norm[o*C+c] fp32
__global__ __launch_bounds__(256) void prep_w(const float* __restrict__ w,
                                              unsigned short* __restrict__ wb,
                                              float* __restrict__ yn) {
    int o = blockIdx.x;
    int tid = threadIdx.x;
    int c = tid >> 6, k = tid & 63;
    size_t idx = (size_t)(o * C_ + c) * K_ + k;
    float v = w[idx];
    wb[idx] = f2bf(v);
    float s = v * v;
    for (int off = 32; off > 0; off >>= 1) s += __shfl_down(s, off, 64);
    if (k == 0) yn[o * C_ + c] = s;
}

// One block = one (n,c) row x one 64-o tile, streaming the FULL l range.
// Wave owns 16 o-rows; lane owns one o-row and stores dwordx4 (4 consecutive l).
__global__ __launch_bounds__(256) void shapelet_main(const float* __restrict__ x,
                                                     const unsigned short* __restrict__ wb,
                                                     const float* __restrict__ yn,
                                                     float* __restrict__ out) {
    __shared__ float xf[XS];            // fp32 x row (exact norms)
    __shared__ unsigned short xs0[XS];  // bf16 copy
    __shared__ unsigned short xs1[XS];  // bf16 copy shifted 1 elem (4B-aligned odd reads)
    __shared__ float xn[D_];            // window sumsq

    int bid = blockIdx.x;
    int otile = bid & 3;
    int nc = bid >> 2;
    int c = nc & (C_ - 1);
    const float* xrow = x + (size_t)nc * D_;
    int tid = threadIdx.x;

    for (int i = tid; i < XS; i += 256) {
        float v = (i < D_) ? xrow[i] : 0.f;
        xf[i] = v;
        unsigned short b = f2bf(v);
        xs0[i] = b;
        if (i > 0) xs1[i - 1] = b;
    }
    __syncthreads();
    for (int l = tid; l < D_; l += 256) {
        float s = 0.f;
        #pragma unroll 16
        for (int k = 0; k < K_; ++k) { float v = xf[l + k]; s = fmaf(v, v, s); }
        xn[l] = s;
    }
    __syncthreads();

    int wave = tid >> 6, lane = tid & 63, lr = lane & 15, hi = lane >> 4;
    int o = otile * 64 + wave * 16 + lr;      // this lane's output row

    s16x8 wfr[2];
    #pragma unroll
    for (int kk = 0; kk < 2; ++kk)
        wfr[kk] = *reinterpret_cast<const s16x8*>(
            wb + ((size_t)o * C_ + c) * K_ + kk * 32 + hi * 8);
    float ynv = yn[o * C_ + c];

    float* orow = out + ((size_t)nc * O_ + o) * L_;
    const unsigned* xs0u = (const unsigned*)xs0;
    const unsigned* xs1u = (const unsigned*)xs1;

    for (int g = 0; g < 32; ++g) {
        int l0 = g * 64;
        f32x4 z = {0.f, 0.f, 0.f, 0.f};
        f32x4 acc[4] = {z, z, z, z};
        #pragma unroll
        for (int t = 0; t < 4; ++t) {
            #pragma unroll
            for (int kk = 0; kk < 2; ++kk) {
                int e = l0 + t * 16 + lr + hi * 8 + kk * 32;
                const unsigned* p = (e & 1) ? (xs1u + ((e - 1) >> 1)) : (xs0u + (e >> 1));
                union { unsigned u[4]; s16x8 v; } bb;
                bb.u[0] = p[0]; bb.u[1] = p[1]; bb.u[2] = p[2]; bb.u[3] = p[3];
                // A = x windows (rows = l), B = weights (cols = o)
                acc[t] = __builtin_amdgcn_mfma_f32_16x16x32_bf16(bb.v, wfr[kk],
                                                                 acc[t], 0, 0, 0);
            }
        }
        if (g < 31) {
            #pragma unroll
            for (int t = 0; t < 4; ++t) {
                int lg = l0 + t * 16 + hi * 4;
                f32x4 xv = *reinterpret_cast<const f32x4*>(&xn[lg]);
                f32x4 r;
                #pragma unroll
                for (int j = 0; j < 4; ++j)
                    r[j] = fmaxf(xv[j] + ynv - 2.f * acc[t][j], 0.f) * (1.f / (float)K_);
                __builtin_memcpy(orow + lg, &r, 16);   // 4B-aligned dwordx4
            }
        } else {
            // tail tile: only l = 1984 is valid
            #pragma unroll
            for (int t = 0; t < 4; ++t) {
                int lg = l0 + t * 16 + hi * 4;
                #pragma unroll
                for (int j = 0; j < 4; ++j) {
                    int l = lg + j;
                    if (l < L_)
                        orow[l] = fmaxf(xn[l] + ynv - 2.f * acc[t][j], 0.f)
                                  * (1.f / (float)K_);
                }
            }
        }
    }
}

extern "C" void kernel_launch(void* const* d_in, const int* in_sizes, int n_in,
                              void* d_out, int out_size, void* d_ws, size_t ws_size,
                              hipStream_t stream) {
    const float* x = (const float*)d_in[0];
    const float* w = (const float*)d_in[1];
    float* out = (float*)d_out;

    unsigned short* wb = (unsigned short*)d_ws;                    // 128 KiB
    float* yn = (float*)((char*)d_ws + (size_t)O_ * C_ * K_ * 2);  // 4 KiB

    prep_w<<<O_, 256, 0, stream>>>(w, wb, yn);
    shapelet_main<<<N_ * C_ * 4, 256, 0, stream>>>(x, wb, yn, out);
}

// Round 3
// 123.236 us; speedup vs baseline: 2.3257x; 1.2105x over previous
//
#include <hip/hip_runtime.h>

#define N_ 64
#define C_ 4
#define D_ 2048
#define K_ 64
#define O_ 256
#define L_ 1985
#define XPAD 2112          // padded x row (D_ + 64)
#define XCOPY 2116         // stride of shifted bf16 copies (shorts): rows 8B-aligned, bank phase 2
#define OPITCH 2020        // staging pitch (floats): >= 2000, mod 32 == 4 (bank spread for b128)
#define NTILE 125          // ceil(L_/16)

typedef __attribute__((ext_vector_type(8))) short s16x8;
typedef __attribute__((ext_vector_type(4))) float f32x4;

__device__ __forceinline__ unsigned short f2bf(float f) {
    union { float f; unsigned u; } v; v.f = f;
    unsigned u = v.u;
    u += 0x7fffu + ((u >> 16) & 1u);   // RNE
    return (unsigned short)(u >> 16);
}

// weight (O,C,K) fp32 -> bf16, plus y_norm[o*C+c]
__global__ __launch_bounds__(256) void prep_w(const float* __restrict__ w,
                                              unsigned short* __restrict__ wb,
                                              float* __restrict__ yn) {
    int o = blockIdx.x;
    int tid = threadIdx.x;
    int c = tid >> 6, k = tid & 63;
    size_t idx = (size_t)(o * C_ + c) * K_ + k;
    float v = w[idx];
    wb[idx] = f2bf(v);
    float s = v * v;
    for (int off = 32; off > 0; off >>= 1) s += __shfl_down(s, off, 64);
    if (k == 0) yn[o * C_ + c] = s;
}

// One block per (n,c). 16 waves. Per super-iter: compute 16 o-rows x full L into
// LDS staging, then each wave drains ONE row as a contiguous ascending stream.
__global__ __launch_bounds__(1024) void shapelet_main(const float* __restrict__ x,
                                                      const unsigned short* __restrict__ wb,
                                                      const float* __restrict__ yn,
                                                      float* __restrict__ out) {
    __shared__ __align__(16) unsigned short xs[4][XCOPY]; // xs[s][i] = bf16(x[i+s])
    __shared__ float xn[D_];
    __shared__ __align__(16) float ost[16 * OPITCH];      // staging; also fp32 x scratch in phase 0

    int nc = blockIdx.x;
    int c = nc & (C_ - 1);
    const float* xrow = x + (size_t)nc * D_;
    int tid = threadIdx.x;

    // phase 0a: x row -> ost (fp32 scratch), zero-padded
    for (int i = tid; i < XPAD; i += 1024) ost[i] = (i < D_) ? xrow[i] : 0.f;
    __syncthreads();
    // phase 0b: four 1-shifted bf16 copies + exact window norms
    for (int i = tid; i < XCOPY; i += 1024) {
        #pragma unroll
        for (int s = 0; s < 4; ++s) {
            int idx = i + s;
            xs[s][i] = (idx < XPAD) ? f2bf(ost[idx]) : (unsigned short)0;
        }
    }
    for (int l = tid; l < D_; l += 1024) {
        float ssum = 0.f;
        #pragma unroll 16
        for (int k = 0; k < K_; ++k) { float v = ost[l + k]; ssum = fmaf(v, v, ssum); }
        xn[l] = ssum;
    }
    __syncthreads();

    int wave = tid >> 6, lane = tid & 63, lr = lane & 15, hi = lane >> 4;
    // per-lane A-fragment base: copy (lr&3) makes every 8B LDS read aligned
    const unsigned short* xbase = &xs[lr & 3][(lr & ~3) + hi * 8];
    int dj = tid & 63;   // drain lane; drain row == wave

    for (int st = 0; st < 16; ++st) {
        int o = st * 16 + lr;
        s16x8 wfr[2];
        #pragma unroll
        for (int kk = 0; kk < 2; ++kk)
            wfr[kk] = *reinterpret_cast<const s16x8*>(
                wb + ((size_t)o * C_ + c) * K_ + kk * 32 + hi * 8);
        float ynv = yn[o * C_ + c];

        // compute 16 rows x full L; wave handles l-tiles t = wave, wave+16, ...
        for (int t = wave; t < NTILE; t += 16) {
            int l0t = t * 16;
            f32x4 acc = {0.f, 0.f, 0.f, 0.f};
            #pragma unroll
            for (int kk = 0; kk < 2; ++kk) {
                const unsigned long long* p =
                    (const unsigned long long*)(xbase + l0t + kk * 32);
                union { unsigned long long u[2]; s16x8 v; } a;
                a.u[0] = p[0]; a.u[1] = p[1];          // 2x ds_read_b64
                acc = __builtin_amdgcn_mfma_f32_16x16x32_bf16(a.v, wfr[kk], acc, 0, 0, 0);
            }
            f32x4 xv = *reinterpret_cast<const f32x4*>(&xn[l0t + hi * 4]);
            f32x4 r;
            #pragma unroll
            for (int j = 0; j < 4; ++j)
                r[j] = fmaxf(xv[j] + ynv - 2.f * acc[j], 0.f) * (1.f / (float)K_);
            *reinterpret_cast<f32x4*>(&ost[lr * OPITCH + l0t + hi * 4]) = r;
        }
        __syncthreads();

        // drain: wave w streams row w contiguously (1KB per wave-inst)
        float* gb = out + ((size_t)nc * O_ + st * 16 + wave) * L_;
        const float* src = &ost[wave * OPITCH];
        for (int pos = dj * 4; pos + 4 <= L_; pos += 256) {
            f32x4 v = *reinterpret_cast<const f32x4*>(src + pos);  // aligned b128
            __builtin_memcpy(gb + pos, &v, 16);                    // contiguous dwordx4
        }
        if (dj == 0) gb[L_ - 1] = src[L_ - 1];
        __syncthreads();
    }
}

extern "C" void kernel_launch(void* const* d_in, const int* in_sizes, int n_in,
                              void* d_out, int out_size, void* d_ws, size_t ws_size,
                              hipStream_t stream) {
    const float* x = (const float*)d_in[0];
    const float* w = (const float*)d_in[1];
    float* out = (float*)d_out;

    unsigned short* wb = (unsigned short*)d_ws;                    // 128 KiB
    float* yn = (float*)((char*)d_ws + (size_t)O_ * C_ * K_ * 2);  // 4 KiB

    prep_w<<<O_, 256, 0, stream>>>(w, wb, yn);
    shapelet_main<<<N_ * C_, 1024, 0, stream>>>(x, wb, yn, out);
}